// Round 4
// baseline (919.136 us; speedup 1.0000x reference)
//
#include <hip/hip_runtime.h>
#include <math.h>

// Problem constants
#define B_ 8
#define T_ 50
#define N_ 1000
#define F_ 4
#define G_ 32
#define H_ 256
#define E_ 32000
#define S_ 5
#define R_ 400        // B*T
#define K0_ 32000     // N*G (LSTM0 input size)
#define NG_ 1024      // 4*H
#define KS_ 16        // split-K factor for big GEMM

#define L0_WGS 8      // layer0: 8 WGs x 128 gate-rows (j-width 32 per gate)
#define L1_WGS 16     // layer1: 16 WGs x 64 gate-rows (j-width 16 per gate)

#define ECHUNK 2048   // gcn_scatter edge chunk (LDS-staged, double-buffered)
#define EHALF (E_ / 2)
#define NCHUNK ((EHALF + ECHUNK - 1) / ECHUNK)  // 8 (7 full + 1664 tail)

typedef unsigned int uint_;
typedef unsigned short ushort_;
typedef unsigned long long u64_;
typedef __attribute__((ext_vector_type(8))) short bf16x8;
typedef __attribute__((ext_vector_type(4))) float f32x4;

static __device__ __forceinline__ float sigm(float x) { return 1.0f / (1.0f + expf(-x)); }

// bf16 round-to-nearest-even split helpers
static __device__ __forceinline__ ushort_ f2bf(float x) {
  uint_ u = __float_as_uint(x);
  u += 0x7FFFu + ((u >> 16) & 1u);
  return (ushort_)(u >> 16);
}
static __device__ __forceinline__ float bf2f(ushort_ b) {
  return __uint_as_float(((uint_)b) << 16);
}
static __device__ __forceinline__ uint_ pk2(float a, float b) {
  return (uint_)f2bf(a) | ((uint_)f2bf(b) << 16);
}
static __device__ __forceinline__ float resid(float x) {
  return x - bf2f(f2bf(x));
}
// split 8 fp32 -> hi/lo bf16x8
static __device__ __forceinline__ void split8(const float* v, bf16x8* hi, bf16x8* lo) {
  bf16x8 h8, l8;
#pragma unroll
  for (int j = 0; j < 8; ++j) {
    ushort_ hb = f2bf(v[j]);
    h8[j] = (short)hb;
    l8[j] = (short)f2bf(v[j] - bf2f(hb));
  }
  *hi = h8; *lo = l8;
}

// async global->LDS 16B
static __device__ __forceinline__ void gload_lds16(const void* g, void* l) {
  __builtin_amdgcn_global_load_lds(
      (const __attribute__((address_space(1))) uint_*)g,
      (__attribute__((address_space(3))) uint_*)l, 16, 0, 0);
}

// ---------------------------------------------------------------------------
// Kernel 1a: GCN scatter (A @ X form).  R4: bulk async edge staging.
// Old version: 125 dependent rounds of scalar 4B edge loads -> latency-bound
// at 278 GB/s (265 cyc/wave-iter ~= HBM latency / 4 waves-per-SIMD).
// New: stage src/dst/ew in 2048-edge chunks via global_load_lds (3x16B per
// thread per chunk, linear), double-buffered; process thread-per-edge out of
// LDS.  Latency exposed once per chunk (8/WG) instead of per iteration.
// LDS: xs 16K + aggX 16K + 2x24K edge bufs = 80KB -> 2 WG/CU, 16 waves.
// ---------------------------------------------------------------------------
__global__ __launch_bounds__(512, 4) void gcn_scatter(
    const float* __restrict__ x, const int* __restrict__ ei,
    const float* __restrict__ ew, float* __restrict__ P) {
  __shared__ __align__(16) float xs[N_ * 4];     // 16 KB (x[n][0..3])
  __shared__ __align__(16) float aggX[N_ * 4];   // 16 KB (f-swizzled)
  __shared__ __align__(16) int   sb[2][ECHUNK];  // 16 KB
  __shared__ __align__(16) int   db[2][ECHUNK];  // 16 KB
  __shared__ __align__(16) float wb[2][ECHUNK];  // 16 KB
  const int r = blockIdx.x >> 1;
  const int eh = blockIdx.x & 1;
  const int tid = threadIdx.x;

  const int* srcp = ei + (size_t)r * 2 * E_ + eh * EHALF;
  const int* dstp = ei + (size_t)r * 2 * E_ + E_ + eh * EHALF;
  const float* ewp = ew + (size_t)r * E_ + eh * EHALF;

  // stage x row-block async (1000x16B: threads 0..499 issue 2 each)
  const float* xrow = x + (size_t)r * (N_ * F_);
  if (tid < 500) {
    gload_lds16(xrow + tid * 4, &xs[tid * 4]);
    gload_lds16(xrow + (500 + tid) * 4, &xs[(500 + tid) * 4]);
  }
  // zero aggX
  {
    float4* av = (float4*)aggX;
    for (int i = tid; i < N_; i += 512) av[i] = make_float4(0.f, 0.f, 0.f, 0.f);
  }
  // stage chunk 0
  {
    const int cnt = (EHALF < ECHUNK) ? EHALF : ECHUNK;
    if (tid < (cnt >> 2)) {
      gload_lds16(srcp + tid * 4, &sb[0][tid * 4]);
      gload_lds16(dstp + tid * 4, &db[0][tid * 4]);
      gload_lds16(ewp + tid * 4, &wb[0][tid * 4]);
    }
  }
  __syncthreads();  // drains vmcnt: xs + chunk0 ready

  int cur = 0;
  for (int c = 0; c < NCHUNK; ++c) {
    // issue next chunk early (drained by the loop-end barrier; the overlap
    // window is this chunk's processing -- T14 issue-early/drain-late)
    if (c + 1 < NCHUNK) {
      const int base = (c + 1) * ECHUNK;
      const int cnt = EHALF - base < ECHUNK ? EHALF - base : ECHUNK;
      const int nxt = cur ^ 1;
      if (tid < (cnt >> 2)) {
        gload_lds16(srcp + base + tid * 4, &sb[nxt][tid * 4]);
        gload_lds16(dstp + base + tid * 4, &db[nxt][tid * 4]);
        gload_lds16(ewp + base + tid * 4, &wb[nxt][tid * 4]);
      }
    }
    const int cnt = EHALF - c * ECHUNK < ECHUNK ? EHALF - c * ECHUNK : ECHUNK;
    for (int i = tid; i < cnt; i += 512) {
      const int s = sb[cur][i], d = db[cur][i];
      const float w = wb[cur][i];
      const float4 xv = *(const float4*)&xs[s << 2];
      const int swz = (d >> 3) & 3;
      unsafeAtomicAdd(&aggX[(d << 2) | swz], w * xv.x);
      unsafeAtomicAdd(&aggX[(d << 2) | (1 ^ swz)], w * xv.y);
      unsafeAtomicAdd(&aggX[(d << 2) | (2 ^ swz)], w * xv.z);
      unsafeAtomicAdd(&aggX[(d << 2) | (3 ^ swz)], w * xv.w);
    }
    __syncthreads();  // all done with cur; next-chunk loads also drained
    cur ^= 1;
  }

  // dump partial (un-swizzled) to global
  float4* pv = (float4*)(P + (size_t)blockIdx.x * (N_ * 4));
  for (int i = tid; i < N_; i += 512) {
    const int swz = (i >> 3) & 3;
    float4 v;
    v.x = aggX[(i << 2) | swz];
    v.y = aggX[(i << 2) | (1 ^ swz)];
    v.z = aggX[(i << 2) | (2 ^ swz)];
    v.w = aggX[(i << 2) | (3 ^ swz)];
    pv[i] = v;
  }
}

// ---------------------------------------------------------------------------
// Kernel 1b: merge partials; emit SPLIT bf16 Zh/Zl pre-permuted (unchanged)
// ---------------------------------------------------------------------------
__global__ __launch_bounds__(256) void gcn_transform(
    const float* __restrict__ P, const float* __restrict__ Wg,
    const float* __restrict__ bg, ushort_* __restrict__ Zh,
    ushort_* __restrict__ Zl) {
  __shared__ float mm[N_ * 4];
  __shared__ float wg[128];
  __shared__ float bgl[32];
  const int r = blockIdx.x;
  const int tid = threadIdx.x;
  const float* P0 = P + (size_t)(2 * r) * (N_ * 4);
  const float* P1 = P0 + N_ * 4;
  for (int i = tid; i < N_ * 4; i += 256) mm[i] = P0[i] + P1[i];
  if (tid < 128) wg[tid] = Wg[tid];
  if (tid < 32) bgl[tid] = bg[tid];
  __syncthreads();

  const int s = (r >> 1) & 3;
  ushort_* zhr = Zh + (size_t)r * K0_;
  ushort_* zlr = Zl + (size_t)r * K0_;
  for (int q = tid; q < 4000; q += 256) {
    const int n = q >> 2, gb = q & 3;
    const float4 a = *(const float4*)&mm[n << 2];
    float z[8];
#pragma unroll
    for (int j = 0; j < 8; ++j) {
      const int g = gb * 8 + j;
      z[j] = tanhf(bgl[g] + a.x * wg[g] + a.y * wg[32 + g] + a.z * wg[64 + g] +
                   a.w * wg[96 + g]);
    }
    uint4 vh, vl;
    vh.x = pk2(z[0], z[1]); vh.y = pk2(z[2], z[3]);
    vh.z = pk2(z[4], z[5]); vh.w = pk2(z[6], z[7]);
    vl.x = pk2(resid(z[0]), resid(z[1])); vl.y = pk2(resid(z[2]), resid(z[3]));
    vl.z = pk2(resid(z[4]), resid(z[5])); vl.w = pk2(resid(z[6]), resid(z[7]));
    const size_t off = (size_t)n * 32 + ((size_t)(gb ^ s) << 3);
    *(uint4*)&zhr[off] = vh;
    *(uint4*)&zlr[off] = vl;
  }
}

// ---------------------------------------------------------------------------
// Kernel 2: bf16x3 MFMA GEMM (unchanged)
// ---------------------------------------------------------------------------
__global__ __launch_bounds__(256, 2) void gemm_x3(
    const ushort_* __restrict__ Zh, const ushort_* __restrict__ Zl,
    const float* __restrict__ W, float* __restrict__ part) {
  const int mt = blockIdx.x;
  const int nt = blockIdx.y;
  const int kz = blockIdx.z;
  const int k0 = (kz < 8) ? kz * 2016 : 16128 + (kz - 8) * 1984;
  const int nsteps = (kz < 8) ? 63 : 62;

  __shared__ __align__(16) ushort_ Ah[128 * 32];
  __shared__ __align__(16) ushort_ Al[128 * 32];
  __shared__ __align__(16) ushort_ Bh[128 * 32];
  __shared__ __align__(16) ushort_ Bl[128 * 32];

  const int tid = threadIdx.x;
  const int lane = tid & 63, wv = tid >> 6;
  const int wr = wv >> 1, wc = wv & 1;

  const int ar0 = tid >> 2, ap = tid & 3;
  const int ar1 = 64 + (tid >> 2);
  const ushort_* zh0 = Zh + (size_t)(mt * 128 + ar0) * K0_ + k0 + ap * 8;
  const ushort_* zh1 = Zh + (size_t)(mt * 128 + ar1) * K0_ + k0 + ap * 8;
  const ushort_* zl0 = Zl + (size_t)(mt * 128 + ar0) * K0_ + k0 + ap * 8;
  const ushort_* zl1 = Zl + (size_t)(mt * 128 + ar1) * K0_ + k0 + ap * 8;

  const int bn = tid >> 1, bh2 = tid & 1;
  const int sB = (bn >> 1) & 3;
  const int q0 = (bh2 * 2) ^ sB, q1 = (bh2 * 2 + 1) ^ sB;
  const float* wrow = W + (size_t)(nt * 128 + bn) * K0_ + k0 + bh2 * 16;

  f32x4 acc[4][4];
#pragma unroll
  for (int i = 0; i < 4; ++i)
#pragma unroll
    for (int j = 0; j < 4; ++j) acc[i][j] = (f32x4){0.f, 0.f, 0.f, 0.f};

  for (int st = 0; st < nsteps; ++st) {
    gload_lds16(zh0, &Ah[(size_t)tid * 8]);
    gload_lds16(zh1, &Ah[2048 + (size_t)tid * 8]);
    gload_lds16(zl0, &Al[(size_t)tid * 8]);
    gload_lds16(zl1, &Al[2048 + (size_t)tid * 8]);
    zh0 += 32; zh1 += 32; zl0 += 32; zl1 += 32;

    const float4 w0 = *(const float4*)(wrow);
    const float4 w1 = *(const float4*)(wrow + 4);
    const float4 w2 = *(const float4*)(wrow + 8);
    const float4 w3 = *(const float4*)(wrow + 12);
    wrow += 32;
    uint4 ha, hb, la, lb;
    ha.x = pk2(w0.x, w0.y); ha.y = pk2(w0.z, w0.w);
    ha.z = pk2(w1.x, w1.y); ha.w = pk2(w1.z, w1.w);
    la.x = pk2(resid(w0.x), resid(w0.y)); la.y = pk2(resid(w0.z), resid(w0.w));
    la.z = pk2(resid(w1.x), resid(w1.y)); la.w = pk2(resid(w1.z), resid(w1.w));
    hb.x = pk2(w2.x, w2.y); hb.y = pk2(w2.z, w2.w);
    hb.z = pk2(w3.x, w3.y); hb.w = pk2(w3.z, w3.w);
    lb.x = pk2(resid(w2.x), resid(w2.y)); lb.y = pk2(resid(w2.z), resid(w2.w));
    lb.z = pk2(resid(w3.x), resid(w3.y)); lb.w = pk2(resid(w3.z), resid(w3.w));
    *(uint4*)&Bh[bn * 32 + q0 * 8] = ha;
    *(uint4*)&Bh[bn * 32 + q1 * 8] = hb;
    *(uint4*)&Bl[bn * 32 + q0 * 8] = la;
    *(uint4*)&Bl[bn * 32 + q1 * 8] = lb;

    __syncthreads();

    bf16x8 afh[4], afl[4], bfh[4], bfl[4];
#pragma unroll
    for (int i = 0; i < 4; ++i) {
      const int arow = wr * 64 + i * 16 + (lane & 15);
      const int aq = (lane >> 4) ^ ((arow >> 1) & 3);
      afh[i] = *(const bf16x8*)&Ah[arow * 32 + aq * 8];
      afl[i] = *(const bf16x8*)&Al[arow * 32 + aq * 8];
      const int brow = wc * 64 + i * 16 + (lane & 15);
      const int bq = (lane >> 4) ^ ((brow >> 1) & 3);
      bfh[i] = *(const bf16x8*)&Bh[brow * 32 + bq * 8];
      bfl[i] = *(const bf16x8*)&Bl[brow * 32 + bq * 8];
    }
#pragma unroll
    for (int i = 0; i < 4; ++i)
#pragma unroll
      for (int j = 0; j < 4; ++j) {
        acc[i][j] = __builtin_amdgcn_mfma_f32_16x16x32_bf16(afh[i], bfh[j], acc[i][j], 0, 0, 0);
        acc[i][j] = __builtin_amdgcn_mfma_f32_16x16x32_bf16(afh[i], bfl[j], acc[i][j], 0, 0, 0);
        acc[i][j] = __builtin_amdgcn_mfma_f32_16x16x32_bf16(afl[i], bfh[j], acc[i][j], 0, 0, 0);
      }
    __syncthreads();
  }

  const int crow0 = mt * 128 + wr * 64 + ((lane >> 4) << 2);
  const int ccol = nt * 128 + wc * 64 + (lane & 15);
  float* pbase = part + (size_t)kz * R_ * NG_;
#pragma unroll
  for (int i = 0; i < 4; ++i)
#pragma unroll
    for (int rr = 0; rr < 4; ++rr) {
      const int gr = crow0 + i * 16 + rr;
      if (gr < R_) {
#pragma unroll
        for (int j = 0; j < 4; ++j)
          pbase[(size_t)gr * NG_ + ccol + j * 16] = acc[i][j][rr];
      }
    }
}

// ---------------------------------------------------------------------------
// Kernel 3: reduce split-K partials + input-side biases -> G0[400][1024]
// ---------------------------------------------------------------------------
__global__ __launch_bounds__(256) void reduce_kernel(
    const float* __restrict__ part, const float* __restrict__ bih0,
    const float* __restrict__ bhh0, float* __restrict__ G0) {
  const int idx = blockIdx.x * 256 + threadIdx.x;
  if (idx >= R_ * NG_) return;
  const int n = idx & (NG_ - 1);
  float s = bih0[n] + bhh0[n];
#pragma unroll
  for (int ks = 0; ks < KS_; ++ks) s += part[(size_t)ks * R_ * NG_ + idx];
  G0[idx] = s;
}

// ---------------------------------------------------------------------------
// Kernel 4: persistent 2-layer LSTM, MFMA recurrence (unchanged from R3).
// ---------------------------------------------------------------------------
__device__ __forceinline__ void wait_cnt_rlx(unsigned* p, unsigned want) {
  unsigned tries = 0;
  while (__hip_atomic_load(p, __ATOMIC_RELAXED, __HIP_MEMORY_SCOPE_AGENT) < want) {
    __builtin_amdgcn_s_sleep(1);
    if (++tries > (1u << 24)) break;  // bail instead of hanging
  }
}

__global__ __launch_bounds__(256, 1) void recur2(
    const float* __restrict__ G0, const float* __restrict__ Whh0,
    const float* __restrict__ Wih1, const float* __restrict__ Whh1,
    const float* __restrict__ bih1, const float* __restrict__ bhh1,
    uint_* __restrict__ h1p, uint_* __restrict__ h2p, float* __restrict__ h2f,
    unsigned* __restrict__ cnt0, unsigned* __restrict__ cnt1) {
  const int wg = blockIdx.x;
  const int tid = threadIdx.x;
  const bool is1 = wg >= L0_WGS;
  const int w = is1 ? wg - L0_WGS : wg;
  const int lane = tid & 63;
  const int wv = tid >> 6;  // wave id == gate q

  __shared__ __align__(16) ushort_ AfH[16 * 64 * 8];  // 16 KB
  __shared__ __align__(16) ushort_ AfL[16 * 64 * 8];  // 16 KB
  __shared__ float gates[4 * 8 * 32];
  __shared__ float cs[256];

  bf16x8 BH[16], BL[16];
  if (!is1) {
#pragma unroll
    for (int nt2 = 0; nt2 < 2; ++nt2) {
      const int n = wv * 256 + w * 32 + nt2 * 16 + (lane & 15);
      const float* wr = Whh0 + (size_t)n * 256 + (lane >> 4) * 8;
#pragma unroll
      for (int s = 0; s < 8; ++s) {
        float v[8];
        *(float4*)&v[0] = *(const float4*)(wr + s * 32);
        *(float4*)&v[4] = *(const float4*)(wr + s * 32 + 4);
        split8(v, &BH[nt2 * 8 + s], &BL[nt2 * 8 + s]);
      }
    }
  } else {
    const int n = wv * 256 + w * 16 + (lane & 15);
    const float* wr1 = Wih1 + (size_t)n * 256 + (lane >> 4) * 8;
    const float* wr2 = Whh1 + (size_t)n * 256 + (lane >> 4) * 8;
#pragma unroll
    for (int s = 0; s < 16; ++s) {
      const float* wr = (s < 8) ? (wr1 + s * 32) : (wr2 + (s - 8) * 32);
      float v[8];
      *(float4*)&v[0] = *(const float4*)wr;
      *(float4*)&v[4] = *(const float4*)(wr + 4);
      split8(v, &BH[s], &BL[s]);
    }
  }

  {
    uint_* a32 = (uint_*)AfH;
    uint_* b32 = (uint_*)AfL;
    for (int i = tid; i < 4096; i += 256) { a32[i] = 0u; b32[i] = 0u; }
    cs[tid] = 0.f;
  }
  float bias1 = 0.f;
  if (is1) {
    const int n = wv * 256 + w * 16 + (lane & 15);
    bias1 = bih1[n] + bhh1[n];
  }
  __syncthreads();

  for (int t = 0; t < T_; ++t) {
    float g0v[2][4];
    if (!is1) {
#pragma unroll
      for (int nt2 = 0; nt2 < 2; ++nt2)
#pragma unroll
        for (int rr = 0; rr < 4; ++rr) {
          const int m = (lane >> 4) * 4 + rr;
          g0v[nt2][rr] = (m < 8)
              ? G0[(size_t)(m * T_ + t) * NG_ + wv * 256 + w * 32 + nt2 * 16 + (lane & 15)]
              : 0.f;
        }
    }
    if (tid == 0) {
      if (!is1) {
        if (t > 0) wait_cnt_rlx(&cnt0[t - 1], L0_WGS);
      } else {
        wait_cnt_rlx(&cnt0[t], L0_WGS);
        if (t > 0) wait_cnt_rlx(&cnt1[t - 1], L1_WGS);
      }
    }
    __syncthreads();

    if (!is1) {
      const int m = tid >> 5, c8 = tid & 31;
      const u64_* src = (const u64_*)(h1p + (size_t)t * 2048 + m * 256 + c8 * 8);
      u64_ d[4];
#pragma unroll
      for (int p = 0; p < 4; ++p)
        d[p] = __hip_atomic_load(src + p, __ATOMIC_RELAXED, __HIP_MEMORY_SCOPE_AGENT);
      bf16x8 hh, hl;
#pragma unroll
      for (int p = 0; p < 4; ++p) {
        const uint_ v0 = (uint_)d[p], v1 = (uint_)(d[p] >> 32);
        hh[p * 2] = (short)(v0 & 0xffffu); hl[p * 2] = (short)(v0 >> 16);
        hh[p * 2 + 1] = (short)(v1 & 0xffffu); hl[p * 2 + 1] = (short)(v1 >> 16);
      }
      const int s = c8 >> 2, sub = c8 & 3, ln = m + sub * 16;
      *(bf16x8*)&AfH[(s * 64 + ln) * 8] = hh;
      *(bf16x8*)&AfL[(s * 64 + ln) * 8] = hl;
    } else {
#pragma unroll
      for (int cc = 0; cc < 2; ++cc) {
        const int c = tid + cc * 256;
        const int m = c >> 6, c8 = c & 63, k = c8 * 8;
        const uint_* bp = (k < 256) ? (h1p + (size_t)(t + 1) * 2048 + m * 256 + k)
                                    : (h2p + (size_t)t * 2048 + m * 256 + (k - 256));
        const u64_* src = (const u64_*)bp;
        u64_ d[4];
#pragma unroll
        for (int p = 0; p < 4; ++p)
          d[p] = __hip_atomic_load(src + p, __ATOMIC_RELAXED, __HIP_MEMORY_SCOPE_AGENT);
        bf16x8 hh, hl;
#pragma unroll
        for (int p = 0; p < 4; ++p) {
          const uint_ v0 = (uint_)d[p], v1 = (uint_)(d[p] >> 32);
          hh[p * 2] = (short)(v0 & 0xffffu); hl[p * 2] = (short)(v0 >> 16);
          hh[p * 2 + 1] = (short)(v1 & 0xffffu); hl[p * 2 + 1] = (short)(v1 >> 16);
        }
        const int s = c8 >> 2, sub = c8 & 3, ln = m + sub * 16;
        *(bf16x8*)&AfH[(s * 64 + ln) * 8] = hh;
        *(bf16x8*)&AfL[(s * 64 + ln) * 8] = hl;
      }
    }
    __syncthreads();

    f32x4 acc0 = (f32x4){0.f, 0.f, 0.f, 0.f};
    f32x4 acc1 = (f32x4){0.f, 0.f, 0.f, 0.f};
    if (!is1) {
#pragma unroll
      for (int s = 0; s < 8; ++s) {
        const bf16x8 ah = *(const bf16x8*)&AfH[(s * 64 + lane) * 8];
        const bf16x8 al = *(const bf16x8*)&AfL[(s * 64 + lane) * 8];
        acc0 = __builtin_amdgcn_mfma_f32_16x16x32_bf16(ah, BH[s], acc0, 0, 0, 0);
        acc0 = __builtin_amdgcn_mfma_f32_16x16x32_bf16(ah, BL[s], acc0, 0, 0, 0);
        acc0 = __builtin_amdgcn_mfma_f32_16x16x32_bf16(al, BH[s], acc0, 0, 0, 0);
        acc1 = __builtin_amdgcn_mfma_f32_16x16x32_bf16(ah, BH[8 + s], acc1, 0, 0, 0);
        acc1 = __builtin_amdgcn_mfma_f32_16x16x32_bf16(ah, BL[8 + s], acc1, 0, 0, 0);
        acc1 = __builtin_amdgcn_mfma_f32_16x16x32_bf16(al, BH[8 + s], acc1, 0, 0, 0);
      }
    } else {
#pragma unroll
      for (int s = 0; s < 16; ++s) {
        const bf16x8 ah = *(const bf16x8*)&AfH[(s * 64 + lane) * 8];
        const bf16x8 al = *(const bf16x8*)&AfL[(s * 64 + lane) * 8];
        acc0 = __builtin_amdgcn_mfma_f32_16x16x32_bf16(ah, BH[s], acc0, 0, 0, 0);
        acc0 = __builtin_amdgcn_mfma_f32_16x16x32_bf16(ah, BL[s], acc0, 0, 0, 0);
        acc0 = __builtin_amdgcn_mfma_f32_16x16x32_bf16(al, BH[s], acc0, 0, 0, 0);
      }
    }

    if (!is1) {
#pragma unroll
      for (int rr = 0; rr < 4; ++rr) {
        const int m = (lane >> 4) * 4 + rr;
        if (m < 8) {
          gates[(wv * 8 + m) * 32 + (lane & 15)] = acc0[rr] + g0v[0][rr];
          gates[(wv * 8 + m) * 32 + 16 + (lane & 15)] = acc1[rr] + g0v[1][rr];
        }
      }
    } else {
#pragma unroll
      for (int rr = 0; rr < 4; ++rr) {
        const int m = (lane >> 4) * 4 + rr;
        if (m < 8) gates[(wv * 8 + m) * 16 + (lane & 15)] = acc0[rr] + bias1;
      }
    }
    __syncthreads();

    if (!is1) {
      const int m = tid >> 5, j = tid & 31;
      const float gi = gates[(0 * 8 + m) * 32 + j];
      const float gf = gates[(1 * 8 + m) * 32 + j];
      const float gg = gates[(2 * 8 + m) * 32 + j];
      const float go = gates[(3 * 8 + m) * 32 + j];
      float c = sigm(gf) * cs[tid] + sigm(gi) * tanhf(gg);
      cs[tid] = c;
      const float h = sigm(go) * tanhf(c);
      const ushort_ hh = f2bf(h);
      const ushort_ hl = f2bf(h - bf2f(hh));
      __hip_atomic_store(h1p + (size_t)(t + 1) * 2048 + m * 256 + w * 32 + j,
                         (uint_)hh | ((uint_)hl << 16), __ATOMIC_RELAXED,
                         __HIP_MEMORY_SCOPE_AGENT);
    } else if (tid < 128) {
      const int m = tid >> 4, j = tid & 15;
      const float gi = gates[(0 * 8 + m) * 16 + j];
      const float gf = gates[(1 * 8 + m) * 16 + j];
      const float gg = gates[(2 * 8 + m) * 16 + j];
      const float go = gates[(3 * 8 + m) * 16 + j];
      float c = sigm(gf) * cs[tid] + sigm(gi) * tanhf(gg);
      cs[tid] = c;
      const float h = sigm(go) * tanhf(c);
      const ushort_ hh = f2bf(h);
      const ushort_ hl = f2bf(h - bf2f(hh));
      __hip_atomic_store(h2p + (size_t)(t + 1) * 2048 + m * 256 + w * 16 + j,
                         (uint_)hh | ((uint_)hl << 16), __ATOMIC_RELAXED,
                         __HIP_MEMORY_SCOPE_AGENT);
      if (t == T_ - 1) h2f[m * 256 + w * 16 + j] = h;  // exact fp32 for FC head
    }
    __syncthreads();
    if (tid == 0) {
      __hip_atomic_fetch_add(is1 ? &cnt1[t] : &cnt0[t], 1u, __ATOMIC_RELEASE,
                             __HIP_MEMORY_SCOPE_AGENT);
    }
  }
}

// ---------------------------------------------------------------------------
// Kernel 5: FC head (unchanged; reads fp32 h2 final state)
// ---------------------------------------------------------------------------
__global__ __launch_bounds__(256) void fc_kernel(
    const float* __restrict__ h2last, const float* __restrict__ fcW,
    const float* __restrict__ fcb, float* __restrict__ out) {
  __shared__ float tl[2048];
  const int tid = threadIdx.x;
  for (int i = tid; i < 2048; i += 256) tl[i] = tanhf(h2last[i]);
  __syncthreads();
  const int nidx = blockIdx.x * 256 + tid;
  if (nidx >= S_ * N_ * F_) return;
  float accv[8];
#pragma unroll
  for (int m2 = 0; m2 < 8; ++m2) accv[m2] = 0.f;
  const float* wr = fcW + (size_t)nidx * 256;
  for (int k = 0; k < 256; k += 4) {
    float4 w4 = *(const float4*)(wr + k);
#pragma unroll
    for (int m2 = 0; m2 < 8; ++m2) {
      float4 t4 = *(const float4*)&tl[m2 * 256 + k];
      accv[m2] += w4.x * t4.x + w4.y * t4.y + w4.z * t4.z + w4.w * t4.w;
    }
  }
  const float bv = fcb[nidx];
#pragma unroll
  for (int m2 = 0; m2 < 8; ++m2) out[(size_t)m2 * (S_ * N_ * F_) + nidx] = accv[m2] + bv;
}

// ---------------------------------------------------------------------------
// Launch: workspace layout (floats):
//   Zh    @ 0          : 400*32000 bf16 = 6,400,000 floats
//   Zl    @ 6,400,000  : 400*32000 bf16 = 6,400,000 floats
//   part  @ 12,800,000 : 16*400*1024    = 6,553,600  (also GCN partials; h2f)
//   G0    @ 19,353,600 : 400*1024       =   409,600
//   h1p   @ 19,763,200 : 51*2048 u32    =   104,448
//   h2p   @ 19,867,648 : 51*2048 u32    =   104,448
//   flags @ 19,972,096 : 128 uint
// ---------------------------------------------------------------------------
extern "C" void kernel_launch(void* const* d_in, const int* in_sizes, int n_in,
                              void* d_out, int out_size, void* d_ws, size_t ws_size,
                              hipStream_t stream) {
  const float* x    = (const float*)d_in[0];
  const int*   ei   = (const int*)d_in[1];
  const float* ew   = (const float*)d_in[2];
  const float* Wg   = (const float*)d_in[3];
  const float* bg   = (const float*)d_in[4];
  const float* Wih0 = (const float*)d_in[5];
  const float* Whh0 = (const float*)d_in[6];
  const float* bih0 = (const float*)d_in[7];
  const float* bhh0 = (const float*)d_in[8];
  const float* Wih1 = (const float*)d_in[9];
  const float* Whh1 = (const float*)d_in[10];
  const float* bih1 = (const float*)d_in[11];
  const float* bhh1 = (const float*)d_in[12];
  const float* fcW  = (const float*)d_in[13];
  const float* fcb  = (const float*)d_in[14];
  float* out = (float*)d_out;
  float* ws = (float*)d_ws;

  ushort_* Zh = (ushort_*)ws;
  ushort_* Zl = (ushort_*)(ws + 6400000);
  float* part = ws + 12800000;
  float* G0   = ws + 19353600;
  uint_* h1p  = (uint_*)(ws + 19763200);
  uint_* h2p  = (uint_*)(ws + 19867648);
  unsigned* cnt0 = (unsigned*)(ws + 19972096);
  unsigned* cnt1 = cnt0 + 64;
  float* h2f  = part;  // free during recur2; consumed by fc_kernel

  // zero h-state slot0 + flags every call (ws is re-poisoned by harness)
  hipMemsetAsync(h1p, 0, (size_t)(104448 * 2 + 128) * sizeof(float), stream);

  gcn_scatter<<<R_ * 2, 512, 0, stream>>>(x, ei, ew, part);
  gcn_transform<<<R_, 256, 0, stream>>>(part, Wg, bg, Zh, Zl);
  gemm_x3<<<dim3(4, 8, KS_), 256, 0, stream>>>(Zh, Zl, Wih0, part);
  reduce_kernel<<<(R_ * NG_ + 255) / 256, 256, 0, stream>>>(part, bih0, bhh0, G0);
  recur2<<<L0_WGS + L1_WGS, 256, 0, stream>>>(G0, Whh0, Wih1, Whh1, bih1, bhh1,
                                              h1p, h2p, h2f, cnt0, cnt1);
  fc_kernel<<<(S_ * N_ * F_ + 255) / 256, 256, 0, stream>>>(h2f, fcW, fcb, out);
}